// Round 1
// baseline (1797.662 us; speedup 1.0000x reference)
//
#include <hip/hip_runtime.h>
#include <math.h>

#define EDIM 1024
#define SEQ  2048
#define NB   4
#define NH   16
#define HD   64
#define NKB  32        // SEQ / 64 key blocks (bug semantics require exactly 64)
#define QSCALE 0.125f  // 1/sqrt(64)

// ---------------------------------------------------------------------------
// 128x128 fp32 GEMM core: C = X @ W^T   (X:[M,1024], W:[N,1024], both K-major)
// 256 threads, 8x8 per-thread tile (2x2 blocks of 4x4 at +64 offsets),
// BK=16, transposed LDS tiles [k][row] with +4 pad (2-way bank aliasing = free),
// register-prefetch double buffering of the global loads.
// ---------------------------------------------------------------------------
__device__ __forceinline__ void gemm128_core(const float* __restrict__ X,
                                             const float* __restrict__ W,
                                             float (*Xs)[132], float (*Ws)[132],
                                             float acc[8][8],
                                             int row_m, int row_n, int t)
{
    const int tm = t >> 4;        // 0..15
    const int tn = t & 15;        // 0..15
    const int sr = t >> 1;        // 0..127 staging row
    const int sk = (t & 1) * 8;   // 0 or 8 staging k-half

    const float* Xp = X + (size_t)(row_m + sr) * EDIM + sk;
    const float* Wp = W + (size_t)(row_n + sr) * EDIM + sk;

    float4 xa = *(const float4*)(Xp);
    float4 xb = *(const float4*)(Xp + 4);
    float4 wa = *(const float4*)(Wp);
    float4 wb = *(const float4*)(Wp + 4);

    #pragma unroll
    for (int i = 0; i < 8; ++i)
        #pragma unroll
        for (int j = 0; j < 8; ++j) acc[i][j] = 0.f;

    for (int kt = 0; kt < EDIM / 16; ++kt) {
        __syncthreads();  // previous tile's compute done
        Xs[sk + 0][sr] = xa.x; Xs[sk + 1][sr] = xa.y;
        Xs[sk + 2][sr] = xa.z; Xs[sk + 3][sr] = xa.w;
        Xs[sk + 4][sr] = xb.x; Xs[sk + 5][sr] = xb.y;
        Xs[sk + 6][sr] = xb.z; Xs[sk + 7][sr] = xb.w;
        Ws[sk + 0][sr] = wa.x; Ws[sk + 1][sr] = wa.y;
        Ws[sk + 2][sr] = wa.z; Ws[sk + 3][sr] = wa.w;
        Ws[sk + 4][sr] = wb.x; Ws[sk + 5][sr] = wb.y;
        Ws[sk + 6][sr] = wb.z; Ws[sk + 7][sr] = wb.w;
        __syncthreads();

        if (kt + 1 < EDIM / 16) {  // prefetch next tile; waitcnt lands next iter
            const float* xn = Xp + (kt + 1) * 16;
            const float* wn = Wp + (kt + 1) * 16;
            xa = *(const float4*)(xn);
            xb = *(const float4*)(xn + 4);
            wa = *(const float4*)(wn);
            wb = *(const float4*)(wn + 4);
        }

        #pragma unroll
        for (int kk = 0; kk < 16; ++kk) {
            const float4 a0 = *(const float4*)&Xs[kk][4 * tm];
            const float4 a1 = *(const float4*)&Xs[kk][64 + 4 * tm];
            const float4 b0 = *(const float4*)&Ws[kk][4 * tn];
            const float4 b1 = *(const float4*)&Ws[kk][64 + 4 * tn];
            const float av[8] = {a0.x, a0.y, a0.z, a0.w, a1.x, a1.y, a1.z, a1.w};
            const float bv[8] = {b0.x, b0.y, b0.z, b0.w, b1.x, b1.y, b1.z, b1.w};
            #pragma unroll
            for (int i = 0; i < 8; ++i)
                #pragma unroll
                for (int j = 0; j < 8; ++j)
                    acc[i][j] = fmaf(av[i], bv[j], acc[i][j]);
        }
    }
}

// QKV projection: grid (8, 64, 3); z selects weight; stores split-head [B,H,S,hd]
__global__ __launch_bounds__(256)
void qkv_gemm_kernel(const float* __restrict__ X,
                     const float* __restrict__ Wq, const float* __restrict__ Wk,
                     const float* __restrict__ Wv,
                     float* __restrict__ Qo, float* __restrict__ Ko,
                     float* __restrict__ Vo)
{
    __shared__ __align__(16) float Xs[16][132];
    __shared__ __align__(16) float Ws[16][132];

    const float* W = (blockIdx.z == 0) ? Wq : (blockIdx.z == 1) ? Wk : Wv;
    float*       O = (blockIdx.z == 0) ? Qo : (blockIdx.z == 1) ? Ko : Vo;

    const int t = threadIdx.x;
    const int row_m = blockIdx.y * 128;
    const int row_n = blockIdx.x * 128;

    float acc[8][8];
    gemm128_core(X, W, Xs, Ws, acc, row_m, row_n, t);

    const int tm = t >> 4, tn = t & 15;
    #pragma unroll
    for (int ih = 0; ih < 2; ++ih)
        #pragma unroll
        for (int j = 0; j < 4; ++j) {
            const int m = row_m + 4 * tm + j + ih * 64;
            const int bb = m >> 11, s = m & 2047;
            #pragma unroll
            for (int jh = 0; jh < 2; ++jh) {
                const int n = row_n + 4 * tn + jh * 64;
                const int hh = n >> 6, d = n & 63;
                float4 v;
                v.x = acc[ih * 4 + j][jh * 4 + 0];
                v.y = acc[ih * 4 + j][jh * 4 + 1];
                v.z = acc[ih * 4 + j][jh * 4 + 2];
                v.w = acc[ih * 4 + j][jh * 4 + 3];
                *(float4*)(O + ((((size_t)bb * NH + hh) * SEQ + s) * HD + d)) = v;
            }
        }
}

// Output projection + bias: grid (8, 64); row-major [B*S, E] store
__global__ __launch_bounds__(256)
void out_gemm_kernel(const float* __restrict__ X, const float* __restrict__ W,
                     const float* __restrict__ bias, float* __restrict__ O)
{
    __shared__ __align__(16) float Xs[16][132];
    __shared__ __align__(16) float Ws[16][132];

    const int t = threadIdx.x;
    const int row_m = blockIdx.y * 128;
    const int row_n = blockIdx.x * 128;

    float acc[8][8];
    gemm128_core(X, W, Xs, Ws, acc, row_m, row_n, t);

    const int tm = t >> 4, tn = t & 15;
    #pragma unroll
    for (int ih = 0; ih < 2; ++ih)
        #pragma unroll
        for (int j = 0; j < 4; ++j) {
            const int m = row_m + 4 * tm + j + ih * 64;
            #pragma unroll
            for (int jh = 0; jh < 2; ++jh) {
                const int n = row_n + 4 * tn + jh * 64;
                const float4 bz = *(const float4*)(bias + n);
                float4 v;
                v.x = acc[ih * 4 + j][jh * 4 + 0] + bz.x;
                v.y = acc[ih * 4 + j][jh * 4 + 1] + bz.y;
                v.z = acc[ih * 4 + j][jh * 4 + 2] + bz.z;
                v.w = acc[ih * 4 + j][jh * 4 + 3] + bz.w;
                *(float4*)(O + (size_t)m * EDIM + n) = v;
            }
        }
}

// ---------------------------------------------------------------------------
// Flash attention, fp32, faithful to the reference's buggy l-recurrence.
// One workgroup (256 thr) per (b, h, 64-row q-tile). Key blocks of exactly 64.
// LDS: Q^T [d][q], K^T/P shared buffer (K^T during S-GEMM, P during PV), V [k][d].
// Thread (ty,tx): q rows 4ty..+3, k (or d) cols 4tx..+3.
// ---------------------------------------------------------------------------
__global__ __launch_bounds__(256)
void flash_attn_kernel(const float* __restrict__ Q, const float* __restrict__ K,
                       const float* __restrict__ V, float* __restrict__ A)
{
    __shared__ __align__(16) float Qt[64][68];
    __shared__ __align__(16) float KP[64][68];  // K^T, then re-used for P
    __shared__ __align__(16) float Vs[64][68];

    const int t  = threadIdx.x;
    const int qt = blockIdx.x, h = blockIdx.y, b = blockIdx.z;
    const size_t base = (((size_t)b * NH + h) * SEQ) * HD;
    const float* Qp = Q + base + (size_t)qt * 64 * HD;
    const float* Kp = K + base;
    const float* Vp = V + base;

    const int ty = t >> 4, tx = t & 15;
    const int sr = t >> 2, sc4 = (t & 3) * 4;

    // stage Q transposed, pre-scaled by 1/sqrt(hd) (exact: *2^-3)
    #pragma unroll
    for (int j = 0; j < 4; ++j) {
        const int c = sc4 + j * 16;
        const float4 v = *(const float4*)(Qp + (size_t)sr * HD + c);
        Qt[c + 0][sr] = v.x * QSCALE; Qt[c + 1][sr] = v.y * QSCALE;
        Qt[c + 2][sr] = v.z * QSCALE; Qt[c + 3][sr] = v.w * QSCALE;
    }

    float m_run[4] = {-INFINITY, -INFINITY, -INFINITY, -INFINITY};
    float l_run[4] = {0.f, 0.f, 0.f, 0.f};
    float oacc[4][4] = {};

    for (int kb = 0; kb < NKB; ++kb) {
        __syncthreads();  // prev PV done (also Qt ready on iter 0)
        // stage K transposed + V row-major
        #pragma unroll
        for (int j = 0; j < 4; ++j) {
            const int c = sc4 + j * 16;
            const float4 kv = *(const float4*)(Kp + (size_t)(kb * 64 + sr) * HD + c);
            KP[c + 0][sr] = kv.x; KP[c + 1][sr] = kv.y;
            KP[c + 2][sr] = kv.z; KP[c + 3][sr] = kv.w;
            const float4 vv = *(const float4*)(Vp + (size_t)(kb * 64 + sr) * HD + c);
            *(float4*)&Vs[sr][c] = vv;
        }
        __syncthreads();

        // S = (Q*scale) @ K^T : per-thread 4x4
        float s[4][4] = {};
        #pragma unroll 8
        for (int kk = 0; kk < HD; ++kk) {
            const float4 qa = *(const float4*)&Qt[kk][4 * ty];
            const float4 kv = *(const float4*)&KP[kk][4 * tx];
            const float av[4] = {qa.x, qa.y, qa.z, qa.w};
            const float bv[4] = {kv.x, kv.y, kv.z, kv.w};
            #pragma unroll
            for (int j = 0; j < 4; ++j)
                #pragma unroll
                for (int i = 0; i < 4; ++i)
                    s[j][i] = fmaf(av[j], bv[i], s[j][i]);
        }

        // online softmax with the reference's BUGGY l update:
        // l_new = chunk_sum*corr + chunk_sum  (previous l discarded)
        float corr[4];
        #pragma unroll
        for (int j = 0; j < 4; ++j) {
            float mx = fmaxf(fmaxf(s[j][0], s[j][1]), fmaxf(s[j][2], s[j][3]));
            mx = fmaxf(mx, __shfl_xor(mx, 1));
            mx = fmaxf(mx, __shfl_xor(mx, 2));
            mx = fmaxf(mx, __shfl_xor(mx, 4));
            mx = fmaxf(mx, __shfl_xor(mx, 8));
            const float mnew = fmaxf(m_run[j], mx);
            corr[j] = __expf(m_run[j] - mnew);
            m_run[j] = mnew;
            float csum = 0.f;
            #pragma unroll
            for (int i = 0; i < 4; ++i) {
                const float p = __expf(s[j][i] - mnew);
                s[j][i] = p;
                csum += p;
            }
            csum += __shfl_xor(csum, 1);
            csum += __shfl_xor(csum, 2);
            csum += __shfl_xor(csum, 4);
            csum += __shfl_xor(csum, 8);
            l_run[j] = csum * corr[j] + csum;  // BUG preserved
        }

        __syncthreads();  // all lanes done reading K^T from KP
        #pragma unroll
        for (int j = 0; j < 4; ++j) {
            float4 v; v.x = s[j][0]; v.y = s[j][1]; v.z = s[j][2]; v.w = s[j][3];
            *(float4*)&KP[4 * ty + j][4 * tx] = v;
        }
        __syncthreads();

        // oacc = oacc*corr + P @ V
        #pragma unroll
        for (int j = 0; j < 4; ++j)
            #pragma unroll
            for (int i = 0; i < 4; ++i)
                oacc[j][i] *= corr[j];

        #pragma unroll 4
        for (int k0 = 0; k0 < 64; k0 += 4) {
            float4 pr[4], vr[4];
            #pragma unroll
            for (int j = 0; j < 4; ++j) pr[j] = *(const float4*)&KP[4 * ty + j][k0];
            #pragma unroll
            for (int u = 0; u < 4; ++u) vr[u] = *(const float4*)&Vs[k0 + u][4 * tx];
            #pragma unroll
            for (int j = 0; j < 4; ++j) {
                const float pj[4] = {pr[j].x, pr[j].y, pr[j].z, pr[j].w};
                #pragma unroll
                for (int u = 0; u < 4; ++u) {
                    oacc[j][0] = fmaf(pj[u], vr[u].x, oacc[j][0]);
                    oacc[j][1] = fmaf(pj[u], vr[u].y, oacc[j][1]);
                    oacc[j][2] = fmaf(pj[u], vr[u].z, oacc[j][2]);
                    oacc[j][3] = fmaf(pj[u], vr[u].w, oacc[j][3]);
                }
            }
        }
    }

    // epilogue: divide by (buggy) l, store merged [B, S, E]
    #pragma unroll
    for (int j = 0; j < 4; ++j) {
        const int srow = qt * 64 + 4 * ty + j;
        float4 v;
        v.x = oacc[j][0] / l_run[j];
        v.y = oacc[j][1] / l_run[j];
        v.z = oacc[j][2] / l_run[j];
        v.w = oacc[j][3] / l_run[j];
        *(float4*)(A + ((size_t)b * SEQ + srow) * EDIM + (size_t)h * HD + 4 * tx) = v;
    }
}

extern "C" void kernel_launch(void* const* d_in, const int* in_sizes, int n_in,
                              void* d_out, int out_size, void* d_ws, size_t ws_size,
                              hipStream_t stream)
{
    (void)in_sizes; (void)n_in; (void)out_size; (void)ws_size;
    const float* x  = (const float*)d_in[0];
    const float* qw = (const float*)d_in[1];
    const float* kw = (const float*)d_in[2];
    const float* vw = (const float*)d_in[3];
    const float* ow = (const float*)d_in[4];
    const float* ob = (const float*)d_in[5];
    float* out = (float*)d_out;

    // workspace: Q | K | V | merged-attn, 32 MB each (fp32 [B,H,S,hd] / [B,S,E])
    float* Qb = (float*)d_ws;
    float* Kb = Qb + (size_t)NB * NH * SEQ * HD;
    float* Vb = Kb + (size_t)NB * NH * SEQ * HD;
    float* Ab = Vb + (size_t)NB * NH * SEQ * HD;

    dim3 blk(256);
    qkv_gemm_kernel<<<dim3(EDIM / 128, (NB * SEQ) / 128, 3), blk, 0, stream>>>(
        x, qw, kw, vw, Qb, Kb, Vb);
    flash_attn_kernel<<<dim3(NKB, NH, NB), blk, 0, stream>>>(Qb, Kb, Vb, Ab);
    out_gemm_kernel<<<dim3(EDIM / 128, (NB * SEQ) / 128, 1), blk, 0, stream>>>(
        Ab, ow, ob, out);
}

// Round 2
// 684.164 us; speedup vs baseline: 2.6275x; 2.6275x over previous
//
#include <hip/hip_runtime.h>
#include <math.h>

#define EDIM 1024
#define SEQ  2048
#define NB   4
#define NH   16
#define HD   64
#define NKB  32        // SEQ / 64 key blocks (bug semantics require exactly 64)
#define QSCALE 0.125f  // 1/sqrt(64), exact power of two

typedef _Float16 half8  __attribute__((ext_vector_type(8)));
typedef _Float16 half4v __attribute__((ext_vector_type(4)));
typedef _Float16 half2v __attribute__((ext_vector_type(2)));
typedef float    f32x4  __attribute__((ext_vector_type(4)));

#define MFMA16(a, b, c) __builtin_amdgcn_mfma_f32_16x16x32_f16((a), (b), (c), 0, 0, 0)

// fp32 -> (hi, lo) f16 split of a float4. hi = RNE(x); lo = RNE(x - hi).
// |x - hi - lo| <= 2^-22|x|: fp32-grade when recombined via 3 MFMAs.
__device__ __forceinline__ void split4(const float4 v, half4v* hi, half4v* lo) {
    _Float16 h0 = (_Float16)v.x, h1 = (_Float16)v.y,
             h2 = (_Float16)v.z, h3 = (_Float16)v.w;
    half4v h; h[0] = h0; h[1] = h1; h[2] = h2; h[3] = h3;
    half4v l;
    l[0] = (_Float16)(v.x - (float)h0);
    l[1] = (_Float16)(v.y - (float)h1);
    l[2] = (_Float16)(v.z - (float)h2);
    l[3] = (_Float16)(v.w - (float)h3);
    *hi = h; *lo = l;
}

// ---------------------------------------------------------------------------
// f16x3 MFMA GEMM core: C[128x128] = X @ W^T, X:[M,1024] W:[N,1024] K-major.
// 256 thr = 4 waves (2x2 of 64x64), BK=32 (one 16x16x32 MFMA K-step per tile),
// in-kernel fp32->f16 hi/lo split at staging, XOR-swizzled LDS (T2),
// next-tile global loads issued before MFMA phase (overlap).
// ---------------------------------------------------------------------------
__device__ __forceinline__ void gemm_core(const float* __restrict__ X,
                                          const float* __restrict__ W,
                                          int row_m, int row_n,
                                          _Float16* Ah, _Float16* Al,
                                          _Float16* Bh, _Float16* Bl,
                                          f32x4 acc[4][4])
{
    const int t    = threadIdx.x;
    const int lane = t & 63;
    const int wave = t >> 6;
    const int wm   = (wave >> 1) * 64, wn = (wave & 1) * 64;
    const int l15  = lane & 15, l4 = lane >> 4;

    const int srow = t >> 1;          // 0..127
    const int sc16 = (t & 1) * 16;    // 0 or 16 (fp32 col base)

    const float* Xp = X + (size_t)(row_m + srow) * EDIM + sc16;
    const float* Wp = W + (size_t)(row_n + srow) * EDIM + sc16;

    float4 xa[4], wa[4];
    #pragma unroll
    for (int j = 0; j < 4; ++j) {
        xa[j] = *(const float4*)(Xp + 4 * j);
        wa[j] = *(const float4*)(Wp + 4 * j);
    }

    const f32x4 zz = {0.f, 0.f, 0.f, 0.f};
    #pragma unroll
    for (int m = 0; m < 4; ++m)
        #pragma unroll
        for (int n = 0; n < 4; ++n) acc[m][n] = zz;

    for (int kt = 0; kt < EDIM / 32; ++kt) {
        __syncthreads();  // prev tile's fragment reads done
        #pragma unroll
        for (int j = 0; j < 4; ++j) {
            const int col = sc16 + 4 * j;
            // 64B rows, 4x16B slots, swizzle slot ^= row&3 (bank-conflict-free reads)
            const int idx = srow * 32 + (((col >> 3) ^ (srow & 3)) << 3) + (col & 7);
            half4v hi, lo;
            split4(xa[j], &hi, &lo);
            *(half4v*)(Ah + idx) = hi; *(half4v*)(Al + idx) = lo;
            split4(wa[j], &hi, &lo);
            *(half4v*)(Bh + idx) = hi; *(half4v*)(Bl + idx) = lo;
        }
        if (kt + 1 < EDIM / 32) {  // prefetch next K-tile; overlaps MFMA phase
            #pragma unroll
            for (int j = 0; j < 4; ++j) {
                xa[j] = *(const float4*)(Xp + (kt + 1) * 32 + 4 * j);
                wa[j] = *(const float4*)(Wp + (kt + 1) * 32 + 4 * j);
            }
        }
        __syncthreads();

        half8 ah[4], al[4];
        #pragma unroll
        for (int m = 0; m < 4; ++m) {
            const int row  = wm + m * 16 + l15;
            const int slot = l4 ^ (row & 3);
            ah[m] = *(const half8*)(Ah + row * 32 + slot * 8);
            al[m] = *(const half8*)(Al + row * 32 + slot * 8);
        }
        #pragma unroll
        for (int n = 0; n < 4; ++n) {
            const int row  = wn + n * 16 + l15;
            const int slot = l4 ^ (row & 3);
            half8 bh = *(const half8*)(Bh + row * 32 + slot * 8);
            half8 bl = *(const half8*)(Bl + row * 32 + slot * 8);
            #pragma unroll
            for (int m = 0; m < 4; ++m) {
                acc[m][n] = MFMA16(ah[m], bh, acc[m][n]);
                acc[m][n] = MFMA16(ah[m], bl, acc[m][n]);
                acc[m][n] = MFMA16(al[m], bh, acc[m][n]);
            }
        }
    }
}

// QKV projection: grid (8, 64, 3); z selects weight; split-head [B,H,S,hd] store.
// Q is pre-scaled by 1/sqrt(hd) (exact *2^-3) in the epilogue.
__global__ __launch_bounds__(256)
void qkv_mfma(const float* __restrict__ X,
              const float* __restrict__ Wq, const float* __restrict__ Wk,
              const float* __restrict__ Wv,
              float* __restrict__ Qo, float* __restrict__ Ko, float* __restrict__ Vo)
{
    __shared__ __align__(16) _Float16 Ah[128 * 32], Al[128 * 32];
    __shared__ __align__(16) _Float16 Bh[128 * 32], Bl[128 * 32];

    const float* W = (blockIdx.z == 0) ? Wq : (blockIdx.z == 1) ? Wk : Wv;
    float*       O = (blockIdx.z == 0) ? Qo : (blockIdx.z == 1) ? Ko : Vo;
    const float scale = (blockIdx.z == 0) ? QSCALE : 1.f;

    const int row_m = blockIdx.y * 128, row_n = blockIdx.x * 128;
    f32x4 acc[4][4];
    gemm_core(X, W, row_m, row_n, Ah, Al, Bh, Bl, acc);

    const int lane = threadIdx.x & 63, wave = threadIdx.x >> 6;
    const int wm = (wave >> 1) * 64, wn = (wave & 1) * 64;
    const int l15 = lane & 15, l4 = lane >> 4;
    #pragma unroll
    for (int m = 0; m < 4; ++m) {
        #pragma unroll
        for (int r = 0; r < 4; ++r) {
            const int R = row_m + wm + m * 16 + l4 * 4 + r;
            const int bb = R >> 11, s = R & 2047;
            #pragma unroll
            for (int n = 0; n < 4; ++n) {
                const int C = row_n + wn + n * 16 + l15;
                const int hh = C >> 6, d = C & 63;
                O[(((size_t)bb * NH + hh) * SEQ + s) * HD + d] = acc[m][n][r] * scale;
            }
        }
    }
}

// Output projection + bias: grid (8, 64); row-major [B*S, E] store.
__global__ __launch_bounds__(256)
void out_mfma(const float* __restrict__ X, const float* __restrict__ W,
              const float* __restrict__ bias, float* __restrict__ O)
{
    __shared__ __align__(16) _Float16 Ah[128 * 32], Al[128 * 32];
    __shared__ __align__(16) _Float16 Bh[128 * 32], Bl[128 * 32];

    const int row_m = blockIdx.y * 128, row_n = blockIdx.x * 128;
    f32x4 acc[4][4];
    gemm_core(X, W, row_m, row_n, Ah, Al, Bh, Bl, acc);

    const int lane = threadIdx.x & 63, wave = threadIdx.x >> 6;
    const int wm = (wave >> 1) * 64, wn = (wave & 1) * 64;
    const int l15 = lane & 15, l4 = lane >> 4;
    #pragma unroll
    for (int m = 0; m < 4; ++m) {
        #pragma unroll
        for (int r = 0; r < 4; ++r) {
            const int R = row_m + wm + m * 16 + l4 * 4 + r;
            #pragma unroll
            for (int n = 0; n < 4; ++n) {
                const int C = row_n + wn + n * 16 + l15;
                O[(size_t)R * EDIM + C] = acc[m][n][r] + bias[C];
            }
        }
    }
}

// ---------------------------------------------------------------------------
// Flash attention, f16x3 MFMA, faithful to the reference's buggy l-recurrence.
// One block (256 thr = 4 waves) per (b, h, 64-row q-tile); 64-key blocks.
// Wave w owns q-rows [16w, 16w+16). LDS: Q hi/lo, K hi/lo (reused for P), V^T
// hi/lo — all XOR-swizzled (slot ^= row&7) for conflict-free b128 frag reads.
// ---------------------------------------------------------------------------
__global__ __launch_bounds__(256)
void attn_mfma(const float* __restrict__ Q, const float* __restrict__ K,
               const float* __restrict__ V, float* __restrict__ A)
{
    __shared__ __align__(16) _Float16 Qsh[64 * 64], Qsl[64 * 64];
    __shared__ __align__(16) _Float16 KPh[64 * 64], KPl[64 * 64];  // K, then P
    __shared__ __align__(16) _Float16 Vth[64 * 64], Vtl[64 * 64];  // V transposed

    const int t    = threadIdx.x;
    const int lane = t & 63;
    const int wave = t >> 6;
    const int qt = blockIdx.x, h = blockIdx.y, b = blockIdx.z;
    const float* Qp = Q + (((size_t)b * NH + h) * SEQ + (size_t)qt * 64) * HD;
    const float* Kp = K + (((size_t)b * NH + h) * SEQ) * HD;
    const float* Vp = V + (((size_t)b * NH + h) * SEQ) * HD;

    const int l15 = lane & 15, l4 = lane >> 4;

    // ---- stage Q (already pre-scaled by QSCALE in the QKV epilogue) ----
    {
        const int row = t >> 2;
        #pragma unroll
        for (int j = 0; j < 4; ++j) {
            const int col = 4 * (t & 3) + 16 * j;
            float4 v = *(const float4*)(Qp + (size_t)row * HD + col);
            half4v hi, lo; split4(v, &hi, &lo);
            const int idx = row * 64 + (((col >> 3) ^ (row & 7)) << 3) + (col & 7);
            *(half4v*)(Qsh + idx) = hi;
            *(half4v*)(Qsl + idx) = lo;
        }
    }

    // ---- prologue global loads for kb = 0 ----
    const int vkp = (t & 31) * 2;  // V: key pair (vkp, vkp+1)
    const int vdb = t >> 5;        // V: d-block (8 dims)
    float4 kreg[4], vreg[4];
    #pragma unroll
    for (int j = 0; j < 4; ++j)
        kreg[j] = *(const float4*)(Kp + (size_t)(t >> 2) * HD + 4 * (t & 3) + 16 * j);
    vreg[0] = *(const float4*)(Vp + (size_t)vkp * HD + vdb * 8);
    vreg[1] = *(const float4*)(Vp + (size_t)vkp * HD + vdb * 8 + 4);
    vreg[2] = *(const float4*)(Vp + (size_t)(vkp + 1) * HD + vdb * 8);
    vreg[3] = *(const float4*)(Vp + (size_t)(vkp + 1) * HD + vdb * 8 + 4);

    __syncthreads();
    // ---- persistent Q fragments (hoisted out of the key loop) ----
    half8 qfh[2], qfl[2];
    #pragma unroll
    for (int ds = 0; ds < 2; ++ds) {
        const int row  = wave * 16 + l15;
        const int slot = (ds * 4 + l4) ^ (row & 7);
        qfh[ds] = *(const half8*)(Qsh + row * 64 + slot * 8);
        qfl[ds] = *(const half8*)(Qsl + row * 64 + slot * 8);
    }

    float m_run[4], l_run[4];
    #pragma unroll
    for (int r = 0; r < 4; ++r) { m_run[r] = -INFINITY; l_run[r] = 0.f; }
    const f32x4 zz = {0.f, 0.f, 0.f, 0.f};
    f32x4 oacc[4];
    #pragma unroll
    for (int nf = 0; nf < 4; ++nf) oacc[nf] = zz;

    for (int kb = 0; kb < NKB; ++kb) {
        __syncthreads();  // prev PV reads of KP(=P)/Vt done; LDS free
        // ---- stage K hi/lo (swizzled) ----
        {
            const int row = t >> 2;
            #pragma unroll
            for (int j = 0; j < 4; ++j) {
                const int col = 4 * (t & 3) + 16 * j;
                half4v hi, lo; split4(kreg[j], &hi, &lo);
                const int idx = row * 64 + (((col >> 3) ^ (row & 7)) << 3) + (col & 7);
                *(half4v*)(KPh + idx) = hi;
                *(half4v*)(KPl + idx) = lo;
            }
        }
        // ---- stage V transposed: Vt[d][key], packed key-pair writes ----
        {
            #pragma unroll
            for (int u = 0; u < 2; ++u) {
                const float4 a = vreg[u];       // key vkp,   d = vdb*8 + 4u + i
                const float4 c = vreg[2 + u];   // key vkp+1
                const float av[4] = {a.x, a.y, a.z, a.w};
                const float cv[4] = {c.x, c.y, c.z, c.w};
                #pragma unroll
                for (int i = 0; i < 4; ++i) {
                    const int d = vdb * 8 + 4 * u + i;
                    const _Float16 ha = (_Float16)av[i], hc = (_Float16)cv[i];
                    const _Float16 la = (_Float16)(av[i] - (float)ha);
                    const _Float16 lc = (_Float16)(cv[i] - (float)hc);
                    const int idx = d * 64 + (((vkp >> 3) ^ (d & 7)) << 3) + (vkp & 7);
                    half2v hv; hv[0] = ha; hv[1] = hc;
                    half2v lv; lv[0] = la; lv[1] = lc;
                    *(half2v*)(Vth + idx) = hv;
                    *(half2v*)(Vtl + idx) = lv;
                }
            }
        }
        // ---- prefetch next key block (overlaps S + softmax + PV) ----
        if (kb + 1 < NKB) {
            const size_t nb = (size_t)(kb + 1) * 64;
            #pragma unroll
            for (int j = 0; j < 4; ++j)
                kreg[j] = *(const float4*)(Kp + (nb + (t >> 2)) * HD + 4 * (t & 3) + 16 * j);
            vreg[0] = *(const float4*)(Vp + (nb + vkp) * HD + vdb * 8);
            vreg[1] = *(const float4*)(Vp + (nb + vkp) * HD + vdb * 8 + 4);
            vreg[2] = *(const float4*)(Vp + (nb + vkp + 1) * HD + vdb * 8);
            vreg[3] = *(const float4*)(Vp + (nb + vkp + 1) * HD + vdb * 8 + 4);
        }
        __syncthreads();

        // ---- S = (Q*scale) @ K^T  (f16x3) ----
        f32x4 sacc[4];
        #pragma unroll
        for (int nf = 0; nf < 4; ++nf) sacc[nf] = zz;
        #pragma unroll
        for (int nf = 0; nf < 4; ++nf) {
            #pragma unroll
            for (int ds = 0; ds < 2; ++ds) {
                const int row  = nf * 16 + l15;
                const int slot = (ds * 4 + l4) ^ (row & 7);
                half8 bh = *(const half8*)(KPh + row * 64 + slot * 8);
                half8 bl = *(const half8*)(KPl + row * 64 + slot * 8);
                sacc[nf] = MFMA16(qfh[ds], bh, sacc[nf]);
                sacc[nf] = MFMA16(qfh[ds], bl, sacc[nf]);
                sacc[nf] = MFMA16(qfl[ds], bh, sacc[nf]);
            }
        }

        // ---- online softmax with the reference's BUGGY l update ----
        float corr[4], p[4][4];
        #pragma unroll
        for (int r = 0; r < 4; ++r) {
            float mx = fmaxf(fmaxf(sacc[0][r], sacc[1][r]),
                             fmaxf(sacc[2][r], sacc[3][r]));
            mx = fmaxf(mx, __shfl_xor(mx, 1));
            mx = fmaxf(mx, __shfl_xor(mx, 2));
            mx = fmaxf(mx, __shfl_xor(mx, 4));
            mx = fmaxf(mx, __shfl_xor(mx, 8));
            const float mnew = fmaxf(m_run[r], mx);
            corr[r]  = __expf(m_run[r] - mnew);
            m_run[r] = mnew;
            float cs = 0.f;
            #pragma unroll
            for (int nf = 0; nf < 4; ++nf) {
                p[r][nf] = __expf(sacc[nf][r] - mnew);
                cs += p[r][nf];
            }
            cs += __shfl_xor(cs, 1);
            cs += __shfl_xor(cs, 2);
            cs += __shfl_xor(cs, 4);
            cs += __shfl_xor(cs, 8);
            l_run[r] = cs * corr[r] + cs;  // BUG preserved: prev l discarded
        }

        __syncthreads();  // all waves done reading K from KP
        // ---- write P hi/lo over the K buffer ----
        #pragma unroll
        for (int r = 0; r < 4; ++r) {
            const int qrow = wave * 16 + l4 * 4 + r;
            #pragma unroll
            for (int nf = 0; nf < 4; ++nf) {
                const int col = nf * 16 + l15;
                const int idx = qrow * 64 + (((col >> 3) ^ (qrow & 7)) << 3) + (col & 7);
                const _Float16 hp = (_Float16)p[r][nf];
                KPh[idx] = hp;
                KPl[idx] = (_Float16)(p[r][nf] - (float)hp);
            }
        }
        __syncthreads();

        // ---- oacc = oacc*corr + P @ V  (f16x3) ----
        #pragma unroll
        for (int nf = 0; nf < 4; ++nf)
            #pragma unroll
            for (int r = 0; r < 4; ++r)
                oacc[nf][r] *= corr[r];

        half8 pah[2], pal[2];
        #pragma unroll
        for (int ks = 0; ks < 2; ++ks) {
            const int row  = wave * 16 + l15;
            const int slot = (ks * 4 + l4) ^ (row & 7);
            pah[ks] = *(const half8*)(KPh + row * 64 + slot * 8);
            pal[ks] = *(const half8*)(KPl + row * 64 + slot * 8);
        }
        #pragma unroll
        for (int nf = 0; nf < 4; ++nf) {
            #pragma unroll
            for (int ks = 0; ks < 2; ++ks) {
                const int row  = nf * 16 + l15;
                const int slot = (ks * 4 + l4) ^ (row & 7);
                half8 bh = *(const half8*)(Vth + row * 64 + slot * 8);
                half8 bl = *(const half8*)(Vtl + row * 64 + slot * 8);
                oacc[nf] = MFMA16(pah[ks], bh, oacc[nf]);
                oacc[nf] = MFMA16(pah[ks], bl, oacc[nf]);
                oacc[nf] = MFMA16(pal[ks], bh, oacc[nf]);
            }
        }
    }

    // ---- epilogue: divide by (buggy) l, store merged [B, S, E] ----
    #pragma unroll
    for (int nf = 0; nf < 4; ++nf) {
        #pragma unroll
        for (int r = 0; r < 4; ++r) {
            const int qrow = qt * 64 + wave * 16 + l4 * 4 + r;
            const int d = nf * 16 + l15;
            A[((size_t)b * SEQ + qrow) * EDIM + h * HD + d] = oacc[nf][r] / l_run[r];
        }
    }
}

extern "C" void kernel_launch(void* const* d_in, const int* in_sizes, int n_in,
                              void* d_out, int out_size, void* d_ws, size_t ws_size,
                              hipStream_t stream)
{
    (void)in_sizes; (void)n_in; (void)out_size; (void)ws_size;
    const float* x  = (const float*)d_in[0];
    const float* qw = (const float*)d_in[1];
    const float* kw = (const float*)d_in[2];
    const float* vw = (const float*)d_in[3];
    const float* ow = (const float*)d_in[4];
    const float* ob = (const float*)d_in[5];
    float* out = (float*)d_out;

    // workspace: Q | K | V | merged-attn, fp32, 33.55 MB each (proven 134 MB)
    float* Qb = (float*)d_ws;
    float* Kb = Qb + (size_t)NB * NH * SEQ * HD;
    float* Vb = Kb + (size_t)NB * NH * SEQ * HD;
    float* Ab = Vb + (size_t)NB * NH * SEQ * HD;

    dim3 blk(256);
    qkv_mfma<<<dim3(EDIM / 128, (NB * SEQ) / 128, 3), blk, 0, stream>>>(
        x, qw, kw, vw, Qb, Kb, Vb);
    attn_mfma<<<dim3(NKB, NH, NB), blk, 0, stream>>>(Qb, Kb, Vb, Ab);
    out_mfma<<<dim3(EDIM / 128, (NB * SEQ) / 128, 1), blk, 0, stream>>>(
        Ab, ow, ob, out);
}

// Round 3
// 577.648 us; speedup vs baseline: 3.1120x; 1.1844x over previous
//
#include <hip/hip_runtime.h>
#include <math.h>

#define EDIM 1024
#define SEQ  2048
#define NB   4
#define NH   16
#define HD   64
#define NKB  32   // SEQ / 64 key blocks (bug semantics require exactly 64)
// Q pre-scale: 1/sqrt(64) * log2(e)  (scores kept in log2 domain; exp -> exp2)
#define QSC2 0.18033688011112042f

// Global tile formats (produced by qkv_mfma epilogue, consumed by attn_mfma):
//  KV triple per (b,h,kb), 24576 B: [Kh 8KB | Kl 8KB | Vth 8KB]
//    Kh/Kl:  row=key(64) x col=d(64) f16, row stride 128B, 16B slots XOR-swizzled
//            byte = row*128 + (((d>>3) ^ (row&7))<<4) + (d&7)*2
//    Vth:    row=d(64) x col=key(64) f16 (transposed), same swizzle on key
//  Q tile per (b,h,qt), 16384 B: [Qh 8KB | Ql 8KB], same layout as Kh/Kl
#define KVT_BYTES 24576
#define QT_BYTES  16384

typedef _Float16 half8  __attribute__((ext_vector_type(8)));
typedef _Float16 half4v __attribute__((ext_vector_type(4)));
typedef float    f32x4  __attribute__((ext_vector_type(4)));

#define MFMA16(a, b, c) __builtin_amdgcn_mfma_f32_16x16x32_f16((a), (b), (c), 0, 0, 0)

// fp32 -> (hi, lo) f16 split of a float4 (for GEMM staging).
__device__ __forceinline__ void split4(const float4 v, half4v* hi, half4v* lo) {
    _Float16 h0 = (_Float16)v.x, h1 = (_Float16)v.y,
             h2 = (_Float16)v.z, h3 = (_Float16)v.w;
    half4v h; h[0] = h0; h[1] = h1; h[2] = h2; h[3] = h3;
    half4v l;
    l[0] = (_Float16)(v.x - (float)h0);
    l[1] = (_Float16)(v.y - (float)h1);
    l[2] = (_Float16)(v.z - (float)h2);
    l[3] = (_Float16)(v.w - (float)h3);
    *hi = h; *lo = l;
}

// ---------------------------------------------------------------------------
// f16x3 MFMA GEMM core (unchanged from round 2): C[128x128] = X @ W^T.
// ---------------------------------------------------------------------------
__device__ __forceinline__ void gemm_core(const float* __restrict__ X,
                                          const float* __restrict__ W,
                                          int row_m, int row_n,
                                          _Float16* Ah, _Float16* Al,
                                          _Float16* Bh, _Float16* Bl,
                                          f32x4 acc[4][4])
{
    const int t    = threadIdx.x;
    const int lane = t & 63;
    const int wave = t >> 6;
    const int wm   = (wave >> 1) * 64, wn = (wave & 1) * 64;
    const int l15  = lane & 15, l4 = lane >> 4;

    const int srow = t >> 1;
    const int sc16 = (t & 1) * 16;

    const float* Xp = X + (size_t)(row_m + srow) * EDIM + sc16;
    const float* Wp = W + (size_t)(row_n + srow) * EDIM + sc16;

    float4 xa[4], wa[4];
    #pragma unroll
    for (int j = 0; j < 4; ++j) {
        xa[j] = *(const float4*)(Xp + 4 * j);
        wa[j] = *(const float4*)(Wp + 4 * j);
    }

    const f32x4 zz = {0.f, 0.f, 0.f, 0.f};
    #pragma unroll
    for (int m = 0; m < 4; ++m)
        #pragma unroll
        for (int n = 0; n < 4; ++n) acc[m][n] = zz;

    for (int kt = 0; kt < EDIM / 32; ++kt) {
        __syncthreads();
        #pragma unroll
        for (int j = 0; j < 4; ++j) {
            const int col = sc16 + 4 * j;
            const int idx = srow * 32 + (((col >> 3) ^ (srow & 3)) << 3) + (col & 7);
            half4v hi, lo;
            split4(xa[j], &hi, &lo);
            *(half4v*)(Ah + idx) = hi; *(half4v*)(Al + idx) = lo;
            split4(wa[j], &hi, &lo);
            *(half4v*)(Bh + idx) = hi; *(half4v*)(Bl + idx) = lo;
        }
        if (kt + 1 < EDIM / 32) {
            #pragma unroll
            for (int j = 0; j < 4; ++j) {
                xa[j] = *(const float4*)(Xp + (kt + 1) * 32 + 4 * j);
                wa[j] = *(const float4*)(Wp + (kt + 1) * 32 + 4 * j);
            }
        }
        __syncthreads();

        half8 ah[4], al[4];
        #pragma unroll
        for (int m = 0; m < 4; ++m) {
            const int row  = wm + m * 16 + l15;
            const int slot = l4 ^ (row & 3);
            ah[m] = *(const half8*)(Ah + row * 32 + slot * 8);
            al[m] = *(const half8*)(Al + row * 32 + slot * 8);
        }
        #pragma unroll
        for (int n = 0; n < 4; ++n) {
            const int row  = wn + n * 16 + l15;
            const int slot = l4 ^ (row & 3);
            half8 bh = *(const half8*)(Bh + row * 32 + slot * 8);
            half8 bl = *(const half8*)(Bl + row * 32 + slot * 8);
            #pragma unroll
            for (int m = 0; m < 4; ++m) {
                acc[m][n] = MFMA16(ah[m], bh, acc[m][n]);
                acc[m][n] = MFMA16(ah[m], bl, acc[m][n]);
                acc[m][n] = MFMA16(al[m], bh, acc[m][n]);
            }
        }
    }
}

// ---------------------------------------------------------------------------
// QKV projection; epilogue writes the pre-split / pre-swizzled / (V:) pre-
// transposed f16 tile formats directly (no fp32 QKV arrays, no prep kernel).
// ---------------------------------------------------------------------------
__global__ __launch_bounds__(256)
void qkv_mfma(const float* __restrict__ X,
              const float* __restrict__ Wq, const float* __restrict__ Wk,
              const float* __restrict__ Wv,
              char* __restrict__ Qt, char* __restrict__ KVt)
{
    __shared__ __align__(16) _Float16 Ah[128 * 32], Al[128 * 32];
    __shared__ __align__(16) _Float16 Bh[128 * 32], Bl[128 * 32];

    const float* W = (blockIdx.z == 0) ? Wq : (blockIdx.z == 1) ? Wk : Wv;

    const int row_m = blockIdx.y * 128, row_n = blockIdx.x * 128;
    f32x4 acc[4][4];
    gemm_core(X, W, row_m, row_n, Ah, Al, Bh, Bl, acc);

    const int lane = threadIdx.x & 63, wave = threadIdx.x >> 6;
    const int wm = (wave >> 1) * 64, wn = (wave & 1) * 64;
    const int l15 = lane & 15, l4 = lane >> 4;

    // block-uniform tile coordinates (128|2048 so no straddling)
    const int b  = row_m >> 11;
    const int hh = (row_n + wn) >> 6;
    const int kb = ((row_m & 2047) + wm) >> 6;
    const size_t tile = ((size_t)b * NH + hh) * NKB + kb;

    if (blockIdx.z == 2) {
        // V: transposed tile Vth[d][key], hi only, half4v (4 consecutive keys)
        char* vb = KVt + tile * KVT_BYTES + 16384;
        #pragma unroll
        for (int m = 0; m < 4; ++m) {
            const int slot_k = m * 2 + (l4 >> 1);   // key>>3, const over r
            const int koff   = (l4 & 1) * 8;        // (key&7)*2 for r=0
            #pragma unroll
            for (int n = 0; n < 4; ++n) {
                const int d = n * 16 + l15;
                half4v hv;
                #pragma unroll
                for (int r = 0; r < 4; ++r) hv[r] = (_Float16)acc[m][n][r];
                *(half4v*)(vb + d * 128 + ((slot_k ^ (d & 7)) << 4) + koff) = hv;
            }
        }
    } else {
        char* base = (blockIdx.z == 0) ? (Qt + tile * QT_BYTES)
                                       : (KVt + tile * KVT_BYTES);
        const float sc = (blockIdx.z == 0) ? QSC2 : 1.f;
        #pragma unroll
        for (int m = 0; m < 4; ++m)
            #pragma unroll
            for (int r = 0; r < 4; ++r) {
                const int row = m * 16 + l4 * 4 + r;
                const int rb  = row * 128;
                #pragma unroll
                for (int n = 0; n < 4; ++n) {
                    const int byte = rb + (((2 * n + (l15 >> 3)) ^ (row & 7)) << 4)
                                   + (l15 & 7) * 2;
                    const float v = acc[m][n][r] * sc;
                    const _Float16 hi = (_Float16)v;
                    *(_Float16*)(base + byte)        = hi;
                    *(_Float16*)(base + 8192 + byte) = (_Float16)(v - (float)hi);
                }
            }
    }
}

// Output projection + bias (unchanged).
__global__ __launch_bounds__(256)
void out_mfma(const float* __restrict__ X, const float* __restrict__ W,
              const float* __restrict__ bias, float* __restrict__ O)
{
    __shared__ __align__(16) _Float16 Ah[128 * 32], Al[128 * 32];
    __shared__ __align__(16) _Float16 Bh[128 * 32], Bl[128 * 32];

    const int row_m = blockIdx.y * 128, row_n = blockIdx.x * 128;
    f32x4 acc[4][4];
    gemm_core(X, W, row_m, row_n, Ah, Al, Bh, Bl, acc);

    const int lane = threadIdx.x & 63, wave = threadIdx.x >> 6;
    const int wm = (wave >> 1) * 64, wn = (wave & 1) * 64;
    const int l15 = lane & 15, l4 = lane >> 4;
    #pragma unroll
    for (int m = 0; m < 4; ++m) {
        #pragma unroll
        for (int r = 0; r < 4; ++r) {
            const int R = row_m + wm + m * 16 + l4 * 4 + r;
            #pragma unroll
            for (int n = 0; n < 4; ++n) {
                const int C = row_n + wn + n * 16 + l15;
                O[(size_t)R * EDIM + C] = acc[m][n][r] + bias[C];
            }
        }
    }
}

// ---------------------------------------------------------------------------
// Flash attention v3: pre-split global tiles + global_load_lds staging,
// double-buffered; PV = hi*hi only; exp2-domain softmax; XCD head locality.
// ---------------------------------------------------------------------------
__device__ __forceinline__ void stage_tile(const char* g, char* lds,
                                           int wave, int lane)
{
    #pragma unroll
    for (int i = 0; i < 6; ++i) {
        __builtin_amdgcn_global_load_lds(
            (const __attribute__((address_space(1))) void*)(g + wave * 6144 + i * 1024 + lane * 16),
            (__attribute__((address_space(3))) void*)(lds + wave * 6144 + i * 1024),
            16, 0, 0);
    }
}

__global__ __launch_bounds__(256)
void attn_mfma(const char* __restrict__ Qt, const char* __restrict__ KVt,
               float* __restrict__ A)
{
    __shared__ __align__(16) char LDS[2 * KVT_BYTES];  // 48 KB: 2 x [Kh|Kl|Vth]

    const int t    = threadIdx.x;
    const int lane = t & 63;
    const int wave = t >> 6;
    const int l15  = lane & 15, l4 = lane >> 4;

    // XCD-aware mapping: each XCD owns 8 complete (b,h) pairs (KV L2-resident)
    const int wg   = blockIdx.x;        // 0..2047
    const int xcd  = wg & 7;
    const int idx  = wg >> 3;           // 0..255
    const int pair = xcd * 8 + (idx >> 5);  // 0..63
    const int qt   = idx & 31;
    const int b    = pair >> 4;
    const int h    = pair & 15;

    const char* qg  = Qt  + (((size_t)b * NH + h) * NKB + qt) * QT_BYTES;
    const char* kvg = KVt + (((size_t)b * NH + h) * NKB) * (size_t)KVT_BYTES;

    // Q fragments straight from global (pre-scaled, pre-split, pre-swizzled)
    half8 qfh[2], qfl[2];
    #pragma unroll
    for (int ds = 0; ds < 2; ++ds) {
        const int row  = wave * 16 + l15;
        const int slot = (ds * 4 + l4) ^ (row & 7);
        const int off  = row * 128 + slot * 16;
        qfh[ds] = *(const half8*)(qg + off);
        qfl[ds] = *(const half8*)(qg + 8192 + off);
    }

    int buf = 0;
    stage_tile(kvg, LDS, wave, lane);   // kb = 0
    asm volatile("s_waitcnt vmcnt(0)" ::: "memory");
    __syncthreads();

    float m_run[4], l_run[4];
    #pragma unroll
    for (int r = 0; r < 4; ++r) { m_run[r] = -INFINITY; l_run[r] = 0.f; }
    const f32x4 zz = {0.f, 0.f, 0.f, 0.f};
    f32x4 oacc[4];
    #pragma unroll
    for (int nf = 0; nf < 4; ++nf) oacc[nf] = zz;

    for (int kb = 0; kb < NKB; ++kb) {
        char* cb = LDS + buf * KVT_BYTES;
        if (kb + 1 < NKB)  // prefetch next tile into the other buffer
            stage_tile(kvg + (size_t)(kb + 1) * KVT_BYTES,
                       LDS + (buf ^ 1) * KVT_BYTES, wave, lane);

        // ---- S = Q @ K^T (f16x3), log2 domain ----
        f32x4 sacc[4];
        #pragma unroll
        for (int nf = 0; nf < 4; ++nf) sacc[nf] = zz;
        #pragma unroll
        for (int nf = 0; nf < 4; ++nf) {
            #pragma unroll
            for (int ds = 0; ds < 2; ++ds) {
                const int row  = nf * 16 + l15;
                const int slot = (ds * 4 + l4) ^ (row & 7);
                const int off  = row * 128 + slot * 16;
                half8 bh = *(const half8*)(cb + off);
                half8 bl = *(const half8*)(cb + 8192 + off);
                sacc[nf] = MFMA16(qfh[ds], bh, sacc[nf]);
                sacc[nf] = MFMA16(qfh[ds], bl, sacc[nf]);
                sacc[nf] = MFMA16(qfl[ds], bh, sacc[nf]);
            }
        }

        // ---- online softmax (exp2 domain) with the reference's BUGGY l ----
        float corr[4], p[4][4];
        #pragma unroll
        for (int r = 0; r < 4; ++r) {
            float mx = fmaxf(fmaxf(sacc[0][r], sacc[1][r]),
                             fmaxf(sacc[2][r], sacc[3][r]));
            mx = fmaxf(mx, __shfl_xor(mx, 1));
            mx = fmaxf(mx, __shfl_xor(mx, 2));
            mx = fmaxf(mx, __shfl_xor(mx, 4));
            mx = fmaxf(mx, __shfl_xor(mx, 8));
            const float mnew = fmaxf(m_run[r], mx);
            corr[r]  = exp2f(m_run[r] - mnew);
            m_run[r] = mnew;
            float cs = 0.f;
            #pragma unroll
            for (int nf = 0; nf < 4; ++nf) {
                p[r][nf] = exp2f(sacc[nf][r] - mnew);
                cs += p[r][nf];
            }
            cs += __shfl_xor(cs, 1);
            cs += __shfl_xor(cs, 2);
            cs += __shfl_xor(cs, 4);
            cs += __shfl_xor(cs, 8);
            l_run[r] = cs * corr[r] + cs;  // BUG preserved: prev l discarded
        }

        __syncthreads();  // all waves done reading K from this buffer

        // ---- write P (hi only) over the Kh region; wave-local rows ----
        #pragma unroll
        for (int r = 0; r < 4; ++r) {
            const int qrow = wave * 16 + l4 * 4 + r;
            const int rb   = qrow * 128;
            #pragma unroll
            for (int nf = 0; nf < 4; ++nf) {
                *(_Float16*)(cb + rb
                             + (((2 * nf + (l15 >> 3)) ^ (qrow & 7)) << 4)
                             + (l15 & 7) * 2) = (_Float16)p[r][nf];
            }
        }

        // ---- oacc = oacc*corr + P @ V (hi*hi) ----
        #pragma unroll
        for (int nf = 0; nf < 4; ++nf)
            #pragma unroll
            for (int r = 0; r < 4; ++r)
                oacc[nf][r] *= corr[r];

        half8 pa[2];
        #pragma unroll
        for (int ks = 0; ks < 2; ++ks) {
            const int row  = wave * 16 + l15;        // own rows only
            const int slot = (ks * 4 + l4) ^ (row & 7);
            pa[ks] = *(const half8*)(cb + row * 128 + slot * 16);
        }
        #pragma unroll
        for (int nf = 0; nf < 4; ++nf) {
            #pragma unroll
            for (int ks = 0; ks < 2; ++ks) {
                const int row  = nf * 16 + l15;      // d
                const int slot = (ks * 4 + l4) ^ (row & 7);
                half8 vh = *(const half8*)(cb + 16384 + row * 128 + slot * 16);
                oacc[nf] = MFMA16(pa[ks], vh, oacc[nf]);
            }
        }

        asm volatile("s_waitcnt vmcnt(0)" ::: "memory");  // next tile landed
        __syncthreads();
        buf ^= 1;
    }

    // ---- epilogue: divide by (buggy) l, store merged [B, S, E] fp32 ----
    #pragma unroll
    for (int nf = 0; nf < 4; ++nf) {
        #pragma unroll
        for (int r = 0; r < 4; ++r) {
            const int qrow = qt * 64 + wave * 16 + l4 * 4 + r;
            const int d = nf * 16 + l15;
            A[((size_t)b * SEQ + qrow) * EDIM + h * HD + d] = oacc[nf][r] / l_run[r];
        }
    }
}

extern "C" void kernel_launch(void* const* d_in, const int* in_sizes, int n_in,
                              void* d_out, int out_size, void* d_ws, size_t ws_size,
                              hipStream_t stream)
{
    (void)in_sizes; (void)n_in; (void)out_size; (void)ws_size;
    const float* x  = (const float*)d_in[0];
    const float* qw = (const float*)d_in[1];
    const float* kw = (const float*)d_in[2];
    const float* vw = (const float*)d_in[3];
    const float* ow = (const float*)d_in[4];
    const float* ob = (const float*)d_in[5];
    float* out = (float*)d_out;

    // ws: KV tiles 50.3MB | Q tiles 33.6MB | attn-out fp32 33.6MB  (~117MB)
    char*  KVt = (char*)d_ws;
    char*  Qt  = KVt + (size_t)NB * NH * NKB * KVT_BYTES;
    float* Ab  = (float*)(Qt + (size_t)NB * NH * NKB * QT_BYTES);

    dim3 blk(256);
    qkv_mfma<<<dim3(EDIM / 128, (NB * SEQ) / 128, 3), blk, 0, stream>>>(
        x, qw, kw, vw, Qt, KVt);
    attn_mfma<<<dim3(NKB * NH * NB), blk, 0, stream>>>(Qt, KVt, Ab);
    out_mfma<<<dim3(EDIM / 128, (NB * SEQ) / 128, 1), blk, 0, stream>>>(
        Ab, ow, ob, out);
}

// Round 4
// 485.953 us; speedup vs baseline: 3.6992x; 1.1887x over previous
//
#include <hip/hip_runtime.h>
#include <math.h>

#define EDIM 1024
#define SEQ  2048
#define NB   4
#define NH   16
#define HD   64
#define NKB  32   // SEQ / 64 key blocks (bug semantics require exactly 64)
// Q pre-scale: 1/sqrt(64) * log2(e)  (scores in log2 domain; exp -> exp2)
#define QSC2 0.18033688011112042f

// Global tile formats (produced by qkv_mfma epilogue, consumed by attn_mfma):
//  KV tile per (b,h,kb), 16384 B: [Kh 8KB | Vth 8KB]   (K lo dropped: its MFMA
//    term contributes ~4e-4 to log2-scores, 40x below the 0.0156 absmax floor)
//    Kh:   row=key(64) x col=d(64) f16, row stride 128B, 16B slots XOR-swizzled
//          byte = row*128 + (((d>>3) ^ (row&7))<<4) + (d&7)*2
//    Vth:  row=d(64) x col=key(64) f16 (transposed), same swizzle on key
//  Q tile per (b,h,qt64), 16384 B: [Qh 8KB | Ql 8KB], same layout as Kh
#define KVT_BYTES 16384
#define QT_BYTES  16384

typedef _Float16 half8  __attribute__((ext_vector_type(8)));
typedef _Float16 half4v __attribute__((ext_vector_type(4)));
typedef float    f32x4  __attribute__((ext_vector_type(4)));

#define MFMA16(a, b, c) __builtin_amdgcn_mfma_f32_16x16x32_f16((a), (b), (c), 0, 0, 0)

// fp32 -> (hi, lo) f16 split of a float4.
__device__ __forceinline__ void split4(const float4 v, half4v* hi, half4v* lo) {
    _Float16 h0 = (_Float16)v.x, h1 = (_Float16)v.y,
             h2 = (_Float16)v.z, h3 = (_Float16)v.w;
    half4v h; h[0] = h0; h[1] = h1; h[2] = h2; h[3] = h3;
    half4v l;
    l[0] = (_Float16)(v.x - (float)h0);
    l[1] = (_Float16)(v.y - (float)h1);
    l[2] = (_Float16)(v.z - (float)h2);
    l[3] = (_Float16)(v.w - (float)h3);
    *hi = h; *lo = l;
}

__device__ __forceinline__ half4v hi4(const float4 v) {
    half4v h;
    h[0] = (_Float16)v.x; h[1] = (_Float16)v.y;
    h[2] = (_Float16)v.z; h[3] = (_Float16)v.w;
    return h;
}

// ---------------------------------------------------------------------------
// f16x2 MFMA GEMM core: C[128x128] = X @ W^T, X:[M,1024] W:[N,1024] K-major.
// A = X hi-only; B = W hi+lo (dropped A-lo term ~3e-4 on outputs, negligible
// vs the 0.0156 absmax floor). 256 thr = 4 waves (2x2 of 64x64), BK=32.
// ---------------------------------------------------------------------------
__device__ __forceinline__ void gemm_core(const float* __restrict__ X,
                                          const float* __restrict__ W,
                                          int row_m, int row_n,
                                          _Float16* Ah,
                                          _Float16* Bh, _Float16* Bl,
                                          f32x4 acc[4][4])
{
    const int t    = threadIdx.x;
    const int lane = t & 63;
    const int wave = t >> 6;
    const int wm   = (wave >> 1) * 64, wn = (wave & 1) * 64;
    const int l15  = lane & 15, l4 = lane >> 4;

    const int srow = t >> 1;
    const int sc16 = (t & 1) * 16;

    const float* Xp = X + (size_t)(row_m + srow) * EDIM + sc16;
    const float* Wp = W + (size_t)(row_n + srow) * EDIM + sc16;

    float4 xa[4], wa[4];
    #pragma unroll
    for (int j = 0; j < 4; ++j) {
        xa[j] = *(const float4*)(Xp + 4 * j);
        wa[j] = *(const float4*)(Wp + 4 * j);
    }

    const f32x4 zz = {0.f, 0.f, 0.f, 0.f};
    #pragma unroll
    for (int m = 0; m < 4; ++m)
        #pragma unroll
        for (int n = 0; n < 4; ++n) acc[m][n] = zz;

    for (int kt = 0; kt < EDIM / 32; ++kt) {
        __syncthreads();
        #pragma unroll
        for (int j = 0; j < 4; ++j) {
            const int col = sc16 + 4 * j;
            const int idx = srow * 32 + (((col >> 3) ^ (srow & 3)) << 3) + (col & 7);
            *(half4v*)(Ah + idx) = hi4(xa[j]);
            half4v hi, lo;
            split4(wa[j], &hi, &lo);
            *(half4v*)(Bh + idx) = hi; *(half4v*)(Bl + idx) = lo;
        }
        if (kt + 1 < EDIM / 32) {
            #pragma unroll
            for (int j = 0; j < 4; ++j) {
                xa[j] = *(const float4*)(Xp + (kt + 1) * 32 + 4 * j);
                wa[j] = *(const float4*)(Wp + (kt + 1) * 32 + 4 * j);
            }
        }
        __syncthreads();

        half8 ah[4];
        #pragma unroll
        for (int m = 0; m < 4; ++m) {
            const int row  = wm + m * 16 + l15;
            const int slot = l4 ^ (row & 3);
            ah[m] = *(const half8*)(Ah + row * 32 + slot * 8);
        }
        #pragma unroll
        for (int n = 0; n < 4; ++n) {
            const int row  = wn + n * 16 + l15;
            const int slot = l4 ^ (row & 3);
            half8 bh = *(const half8*)(Bh + row * 32 + slot * 8);
            half8 bl = *(const half8*)(Bl + row * 32 + slot * 8);
            #pragma unroll
            for (int m = 0; m < 4; ++m) {
                acc[m][n] = MFMA16(ah[m], bh, acc[m][n]);
                acc[m][n] = MFMA16(ah[m], bl, acc[m][n]);
            }
        }
    }
}

// ---------------------------------------------------------------------------
// QKV projection; epilogue writes pre-split / pre-swizzled / (V:) pre-
// transposed f16 tile formats. K: hi only. Q: hi+lo. V: transposed hi.
// ---------------------------------------------------------------------------
__global__ __launch_bounds__(256)
void qkv_mfma(const float* __restrict__ X,
              const float* __restrict__ Wq, const float* __restrict__ Wk,
              const float* __restrict__ Wv,
              char* __restrict__ Qt, char* __restrict__ KVt)
{
    __shared__ __align__(16) _Float16 Ah[128 * 32];
    __shared__ __align__(16) _Float16 Bh[128 * 32], Bl[128 * 32];

    const float* W = (blockIdx.z == 0) ? Wq : (blockIdx.z == 1) ? Wk : Wv;

    const int row_m = blockIdx.y * 128, row_n = blockIdx.x * 128;
    f32x4 acc[4][4];
    gemm_core(X, W, row_m, row_n, Ah, Bh, Bl, acc);

    const int lane = threadIdx.x & 63, wave = threadIdx.x >> 6;
    const int wm = (wave >> 1) * 64, wn = (wave & 1) * 64;
    const int l15 = lane & 15, l4 = lane >> 4;

    // block-uniform tile coordinates (128|2048 so no straddling)
    const int b  = row_m >> 11;
    const int hh = (row_n + wn) >> 6;
    const int kb = ((row_m & 2047) + wm) >> 6;
    const size_t tile = ((size_t)b * NH + hh) * NKB + kb;

    if (blockIdx.z == 2) {
        // V: transposed tile Vth[d][key], hi only
        char* vb = KVt + tile * KVT_BYTES + 8192;
        #pragma unroll
        for (int m = 0; m < 4; ++m) {
            const int slot_k = m * 2 + (l4 >> 1);
            const int koff   = (l4 & 1) * 8;
            #pragma unroll
            for (int n = 0; n < 4; ++n) {
                const int d = n * 16 + l15;
                half4v hv;
                #pragma unroll
                for (int r = 0; r < 4; ++r) hv[r] = (_Float16)acc[m][n][r];
                *(half4v*)(vb + d * 128 + ((slot_k ^ (d & 7)) << 4) + koff) = hv;
            }
        }
    } else {
        const bool isQ = (blockIdx.z == 0);
        char* base = isQ ? (Qt + tile * QT_BYTES) : (KVt + tile * KVT_BYTES);
        const float sc = isQ ? QSC2 : 1.f;
        #pragma unroll
        for (int m = 0; m < 4; ++m)
            #pragma unroll
            for (int r = 0; r < 4; ++r) {
                const int row = m * 16 + l4 * 4 + r;
                const int rb  = row * 128;
                #pragma unroll
                for (int n = 0; n < 4; ++n) {
                    const int byte = rb + (((2 * n + (l15 >> 3)) ^ (row & 7)) << 4)
                                   + (l15 & 7) * 2;
                    const float v = acc[m][n][r] * sc;
                    const _Float16 hi = (_Float16)v;
                    *(_Float16*)(base + byte) = hi;
                    if (isQ)
                        *(_Float16*)(base + 8192 + byte) = (_Float16)(v - (float)hi);
                }
            }
    }
}

// Output projection + bias.
__global__ __launch_bounds__(256)
void out_mfma(const float* __restrict__ X, const float* __restrict__ W,
              const float* __restrict__ bias, float* __restrict__ O)
{
    __shared__ __align__(16) _Float16 Ah[128 * 32];
    __shared__ __align__(16) _Float16 Bh[128 * 32], Bl[128 * 32];

    const int row_m = blockIdx.y * 128, row_n = blockIdx.x * 128;
    f32x4 acc[4][4];
    gemm_core(X, W, row_m, row_n, Ah, Bh, Bl, acc);

    const int lane = threadIdx.x & 63, wave = threadIdx.x >> 6;
    const int wm = (wave >> 1) * 64, wn = (wave & 1) * 64;
    const int l15 = lane & 15, l4 = lane >> 4;
    #pragma unroll
    for (int m = 0; m < 4; ++m) {
        #pragma unroll
        for (int r = 0; r < 4; ++r) {
            const int R = row_m + wm + m * 16 + l4 * 4 + r;
            #pragma unroll
            for (int n = 0; n < 4; ++n) {
                const int C = row_n + wn + n * 16 + l15;
                O[(size_t)R * EDIM + C] = acc[m][n][r] + bias[C];
            }
        }
    }
}

// ---------------------------------------------------------------------------
// Flash attention v4: QBLK=128 (4 waves x 32 q-rows), K hi-only S-GEMM,
// chunk-sum via MFMA-ones (no sum shuffles), double-buffered global_load_lds
// staging, separate wave-local P buffer (1 barrier + 1 vmcnt per key block).
// ---------------------------------------------------------------------------
__device__ __forceinline__ void stage_tile16(const char* g, char* lds,
                                             int wave, int lane)
{
    #pragma unroll
    for (int i = 0; i < 4; ++i) {
        __builtin_amdgcn_global_load_lds(
            (const __attribute__((address_space(1))) void*)(g + i * 4096 + wave * 1024 + lane * 16),
            (__attribute__((address_space(3))) void*)(lds + i * 4096 + wave * 1024),
            16, 0, 0);
    }
}

__global__ __launch_bounds__(256)
void attn_mfma(const char* __restrict__ Qt, const char* __restrict__ KVt,
               float* __restrict__ A)
{
    __shared__ __align__(16) char LDS[2 * KVT_BYTES + 16384];  // 48 KB

    const int t    = threadIdx.x;
    const int lane = t & 63;
    const int wave = t >> 6;
    const int l15  = lane & 15, l4 = lane >> 4;

    // XCD-aware mapping: each XCD owns 8 complete (b,h) pairs (KV L2-resident)
    const int wg    = blockIdx.x;       // 0..1023
    const int xcd   = wg & 7;
    const int idx   = wg >> 3;          // 0..127
    const int pair  = xcd * 8 + (idx >> 4);  // 0..63
    const int qt128 = idx & 15;
    const int b     = pair >> 4;
    const int h     = pair & 15;

    const char* qg  = Qt  + (((size_t)b * NH + h) * NKB + qt128 * 2) * (size_t)QT_BYTES;
    const char* kvg = KVt + (((size_t)b * NH + h) * NKB) * (size_t)KVT_BYTES;
    char* Pb = LDS + 2 * KVT_BYTES;     // P: 128 rows x 128B, swizzled like Kh

    const int q0 = wave * 32;           // wave's q-row base within the 128-block

    stage_tile16(kvg, LDS, wave, lane);  // kb = 0

    // Q fragments (pre-scaled, pre-split, pre-swizzled): 2 qtiles x 2 d-slices
    half8 qfh[2][2], qfl[2][2];
    #pragma unroll
    for (int qt = 0; qt < 2; ++qt) {
        const int qr = q0 + qt * 16;
        const char* qtile = qg + (qr >> 6) * QT_BYTES;
        const int row = (qr & 63) + l15;
        #pragma unroll
        for (int ds = 0; ds < 2; ++ds) {
            const int off = row * 128 + (((ds * 4 + l4) ^ (row & 7)) << 4);
            qfh[qt][ds] = *(const half8*)(qtile + off);
            qfl[qt][ds] = *(const half8*)(qtile + 8192 + off);
        }
    }

    half8 ones;
    #pragma unroll
    for (int i = 0; i < 8; ++i) ones[i] = (_Float16)1.0f;

    float m_run[2][4], l_run[2][4], corr[2][4];
    #pragma unroll
    for (int qt = 0; qt < 2; ++qt)
        #pragma unroll
        for (int r = 0; r < 4; ++r) { m_run[qt][r] = -INFINITY; l_run[qt][r] = 0.f; }

    const f32x4 zz = {0.f, 0.f, 0.f, 0.f};
    f32x4 oacc[2][4];
    #pragma unroll
    for (int qt = 0; qt < 2; ++qt)
        #pragma unroll
        for (int nf = 0; nf < 4; ++nf) oacc[qt][nf] = zz;

    int buf = 0;
    for (int kb = 0; kb < NKB; ++kb) {
        asm volatile("s_waitcnt vmcnt(0)" ::: "memory");  // current tile landed
        __syncthreads();   // all waves: tile ready AND prev-buffer reads done
        if (kb + 1 < NKB)
            stage_tile16(kvg + (size_t)(kb + 1) * KVT_BYTES,
                         LDS + (buf ^ 1) * KVT_BYTES, wave, lane);

        const char* cb = LDS + buf * KVT_BYTES;

        // ---- S = Q @ K^T (hi+lo Q, hi K), log2 domain ----
        f32x4 sacc[2][4];
        #pragma unroll
        for (int qt = 0; qt < 2; ++qt)
            #pragma unroll
            for (int nf = 0; nf < 4; ++nf) sacc[qt][nf] = zz;

        __builtin_amdgcn_s_setprio(1);
        #pragma unroll
        for (int nf = 0; nf < 4; ++nf) {
            #pragma unroll
            for (int ds = 0; ds < 2; ++ds) {
                const int row  = nf * 16 + l15;
                const int slot = (ds * 4 + l4) ^ (row & 7);
                half8 bh = *(const half8*)(cb + row * 128 + slot * 16);
                #pragma unroll
                for (int qt = 0; qt < 2; ++qt) {
                    sacc[qt][nf] = MFMA16(qfh[qt][ds], bh, sacc[qt][nf]);
                    sacc[qt][nf] = MFMA16(qfl[qt][ds], bh, sacc[qt][nf]);
                }
            }
        }
        __builtin_amdgcn_s_setprio(0);

        // ---- online softmax max-path (exact block max: semantically required)
        #pragma unroll
        for (int qt = 0; qt < 2; ++qt) {
            #pragma unroll
            for (int r = 0; r < 4; ++r) {
                float mx = fmaxf(fmaxf(sacc[qt][0][r], sacc[qt][1][r]),
                                 fmaxf(sacc[qt][2][r], sacc[qt][3][r]));
                mx = fmaxf(mx, __shfl_xor(mx, 1));
                mx = fmaxf(mx, __shfl_xor(mx, 2));
                mx = fmaxf(mx, __shfl_xor(mx, 4));
                mx = fmaxf(mx, __shfl_xor(mx, 8));
                const float mnew = fmaxf(m_run[qt][r], mx);
                corr[qt][r]  = exp2f(m_run[qt][r] - mnew);
                m_run[qt][r] = mnew;
                #pragma unroll
                for (int nf = 0; nf < 4; ++nf)
                    sacc[qt][nf][r] = exp2f(sacc[qt][nf][r] - mnew);  // p
            }
        }

        // ---- write P (hi) to wave-local rows of Pb ----
        #pragma unroll
        for (int qt = 0; qt < 2; ++qt)
            #pragma unroll
            for (int r = 0; r < 4; ++r) {
                const int qrow = q0 + qt * 16 + l4 * 4 + r;
                const int rb   = qrow * 128;
                #pragma unroll
                for (int nf = 0; nf < 4; ++nf)
                    *(_Float16*)(Pb + rb
                                 + (((2 * nf + (l15 >> 3)) ^ (qrow & 7)) << 4)
                                 + (l15 & 7) * 2) = (_Float16)sacc[qt][nf][r];
            }

        // ---- P fragments (own rows; in-wave write->read, no barrier) ----
        half8 pa[2][2];
        #pragma unroll
        for (int qt = 0; qt < 2; ++qt) {
            const int row = q0 + qt * 16 + l15;
            #pragma unroll
            for (int ks = 0; ks < 2; ++ks) {
                const int slot = (ks * 4 + l4) ^ (row & 7);
                pa[qt][ks] = *(const half8*)(Pb + row * 128 + slot * 16);
            }
        }

        // ---- chunk-sum via MFMA-ones + buggy l update, then scale oacc ----
        #pragma unroll
        for (int qt = 0; qt < 2; ++qt) {
            f32x4 lacc = zz;
            lacc = MFMA16(pa[qt][0], ones, lacc);
            lacc = MFMA16(pa[qt][1], ones, lacc);
            #pragma unroll
            for (int r = 0; r < 4; ++r) {
                const float cs = lacc[r];
                l_run[qt][r] = cs * corr[qt][r] + cs;  // BUG preserved
                #pragma unroll
                for (int nf = 0; nf < 4; ++nf)
                    oacc[qt][nf][r] *= corr[qt][r];
            }
        }

        // ---- oacc += P @ V ----
        __builtin_amdgcn_s_setprio(1);
        #pragma unroll
        for (int nf = 0; nf < 4; ++nf) {
            #pragma unroll
            for (int ks = 0; ks < 2; ++ks) {
                const int row  = nf * 16 + l15;      // d
                const int slot = (ks * 4 + l4) ^ (row & 7);
                half8 vh = *(const half8*)(cb + 8192 + row * 128 + slot * 16);
                #pragma unroll
                for (int qt = 0; qt < 2; ++qt)
                    oacc[qt][nf] = MFMA16(pa[qt][ks], vh, oacc[qt][nf]);
            }
        }
        __builtin_amdgcn_s_setprio(0);

        buf ^= 1;
    }

    // ---- epilogue: divide by (buggy) l, store merged [B, S, E] fp32 ----
    #pragma unroll
    for (int qt = 0; qt < 2; ++qt)
        #pragma unroll
        for (int nf = 0; nf < 4; ++nf)
            #pragma unroll
            for (int r = 0; r < 4; ++r) {
                const int qrow = qt128 * 128 + q0 + qt * 16 + l4 * 4 + r;
                const int d = nf * 16 + l15;
                A[((size_t)b * SEQ + qrow) * EDIM + h * HD + d] =
                    oacc[qt][nf][r] / l_run[qt][r];
            }
}

extern "C" void kernel_launch(void* const* d_in, const int* in_sizes, int n_in,
                              void* d_out, int out_size, void* d_ws, size_t ws_size,
                              hipStream_t stream)
{
    (void)in_sizes; (void)n_in; (void)out_size; (void)ws_size;
    const float* x  = (const float*)d_in[0];
    const float* qw = (const float*)d_in[1];
    const float* kw = (const float*)d_in[2];
    const float* vw = (const float*)d_in[3];
    const float* ow = (const float*)d_in[4];
    const float* ob = (const float*)d_in[5];
    float* out = (float*)d_out;

    // ws: KV tiles 33.6MB | Q tiles 33.6MB | attn-out fp32 33.6MB (~101MB)
    char*  KVt = (char*)d_ws;
    char*  Qt  = KVt + (size_t)NB * NH * NKB * KVT_BYTES;
    float* Ab  = (float*)(Qt + (size_t)NB * NH * NKB * QT_BYTES);

    dim3 blk(256);
    qkv_mfma<<<dim3(EDIM / 128, (NB * SEQ) / 128, 3), blk, 0, stream>>>(
        x, qw, kw, vw, Qt, KVt);
    attn_mfma<<<dim3((SEQ / 128) * NH * NB), blk, 0, stream>>>(Qt, KVt, Ab);
    out_mfma<<<dim3(EDIM / 128, (NB * SEQ) / 128, 1), blk, 0, stream>>>(
        Ab, ow, ob, out);
}